// Round 22
// baseline (60.615 us; speedup 1.0000x reference)
//
#include <hip/hip_runtime.h>
#include <hip/hip_bf16.h>

typedef __attribute__((ext_vector_type(8))) short short8;   // bf16x8 MFMA frag
typedef __attribute__((ext_vector_type(4))) float f32x4;    // fp32x4 acc

#define B_  8
#define T_  2048
#define E_  1024
#define H_  64
#define SCALE 0.03125f   // 1024^-0.5

__device__ inline unsigned short f2bf(float f) {
    unsigned int u = __builtin_bit_cast(unsigned int, f);
    unsigned int r = (u + 0x7FFFu + ((u >> 16) & 1u)) >> 16;   // RNE
    return (unsigned short)r;
}
__device__ inline unsigned int packbf(float lo, float hi) {
    return (unsigned int)f2bf(lo) | ((unsigned int)f2bf(hi) << 16);
}
__device__ inline void glds16(const void* g, void* l) {
    __builtin_amdgcn_global_load_lds((const __attribute__((address_space(1))) void*)g,
                                     (__attribute__((address_space(3))) void*)l, 16, 0, 0);
}

// ------------- kernel 0: W fp32 [1024][64] -> Wt bf16 [192][1024] (transposed) -------
__global__ __launch_bounds__(256) void prep_w(const float* __restrict__ Wq,
                                              const float* __restrict__ Wk,
                                              const float* __restrict__ Wv,
                                              unsigned short* __restrict__ Wt) {
    __shared__ float ls[64][65];
    int tid = threadIdx.x;
    int wsel = blockIdx.x >> 4, kt = blockIdx.x & 15;
    const float* W = (wsel == 0) ? Wq : (wsel == 1) ? Wk : Wv;
    int kr = tid >> 2, c4 = (tid & 3) * 16;
    const float* src = W + (long)(kt * 64 + kr) * H_ + c4;
    #pragma unroll
    for (int i = 0; i < 4; ++i) {
        float4 v = *(const float4*)(src + 4 * i);
        ls[kr][c4 + 4 * i + 0] = v.x; ls[kr][c4 + 4 * i + 1] = v.y;
        ls[kr][c4 + 4 * i + 2] = v.z; ls[kr][c4 + 4 * i + 3] = v.w;
    }
    __syncthreads();
    int c = tid >> 2, kk = (tid & 3) * 16;
    unsigned short* dst = Wt + (long)(wsel * 64 + c) * E_ + kt * 64 + kk;
    uint4 o1, o2;
    o1.x = packbf(ls[kk + 0][c], ls[kk + 1][c]);  o1.y = packbf(ls[kk + 2][c], ls[kk + 3][c]);
    o1.z = packbf(ls[kk + 4][c], ls[kk + 5][c]);  o1.w = packbf(ls[kk + 6][c], ls[kk + 7][c]);
    o2.x = packbf(ls[kk + 8][c], ls[kk + 9][c]);  o2.y = packbf(ls[kk + 10][c], ls[kk + 11][c]);
    o2.z = packbf(ls[kk + 12][c], ls[kk + 13][c]);o2.w = packbf(ls[kk + 14][c], ls[kk + 15][c]);
    *(uint4*)dst = o1;
    *(uint4*)(dst + 8) = o2;
}

// ---------------- kernel 1: QKV GEMM  [16384,1024] @ [1024,192] --------------------
// R15 version (verified; 16.9us measured via duplicate-launch attribution).
__global__ __launch_bounds__(512, 4) void qkv_gemm(const float* __restrict__ x,
                                                   const unsigned short* __restrict__ Wt,
                                                   unsigned short* __restrict__ qb,
                                                   unsigned short* __restrict__ kb,
                                                   unsigned short* __restrict__ vt) {
    __shared__ unsigned short wlds[2][192 * 64];   // 49152 B, linear (glds dest)
    __shared__ unsigned short xlds[2][32 * 72];    // 9216 B, padded stride 144B

    int tid = threadIdx.x, lane = tid & 63, w = tid >> 6;   // 8 waves
    int l15 = lane & 15, lg = lane >> 4;
    int wr = w & 1, wc = w >> 1;                   // row half / col quarter
    int r0 = blockIdx.x * 32;
    int b = r0 >> 11, tb = r0 & 2047;

    int l8 = lane >> 3, s8 = lane & 7;
    int swz = s8 ^ l8;
    const unsigned short* wg = Wt + (long)(24 * w + l8) * E_ + swz * 8;
    unsigned short* wl0 = &wlds[0][(24 * w) * 64];
    unsigned short* wl1 = &wlds[1][(24 * w) * 64];

    int xr = tid >> 4, xcf = (tid & 15) * 4;
    const float* xg = x + (long)(r0 + xr) * E_ + xcf;

    f32x4 acc[3];
    #pragma unroll
    for (int i = 0; i < 3; ++i) acc[i] = (f32x4){0.f, 0.f, 0.f, 0.f};

    {
        float4 xa = *(const float4*)xg;
        #pragma unroll
        for (int j = 0; j < 3; ++j)
            glds16(wg + (long)(8 * j) * E_, wl0 + (8 * j) * 64);
        uint2 ua; ua.x = packbf(xa.x, xa.y); ua.y = packbf(xa.z, xa.w);
        *(uint2*)&xlds[0][xr * 72 + xcf] = ua;
    }

    for (int ks = 0; ks < 16; ++ks) {
        int cur = ks & 1;
        __builtin_amdgcn_s_barrier();              // b1: all waves done with prev compute
        __builtin_amdgcn_sched_barrier(0);
        float4 xa;
        if (ks < 15) {
            int kp = (ks + 1) * 64;
            xa = *(const float4*)(xg + kp);        // 1 vmem
            unsigned short* wldst = cur ? wl0 : wl1;
            #pragma unroll
            for (int j = 0; j < 3; ++j)            // 3 vmem (glds)
                glds16(wg + (long)(8 * j) * E_ + kp, wldst + (8 * j) * 64);
            asm volatile("s_waitcnt vmcnt(4) lgkmcnt(0)" ::: "memory");
        } else {
            asm volatile("s_waitcnt vmcnt(0) lgkmcnt(0)" ::: "memory");
        }
        __builtin_amdgcn_sched_barrier(0);
        __builtin_amdgcn_s_barrier();              // b2: buf cur ready for everyone
        __builtin_amdgcn_sched_barrier(0);

        const char* wb = (const char*)&wlds[cur][0];
        const char* xsb = (const char*)&xlds[cur][0];
        #pragma unroll
        for (int kk2 = 0; kk2 < 2; ++kk2) {
            short8 a = *(const short8*)(xsb + (16 * wr + l15) * 144 + kk2 * 64 + lg * 16);
            #pragma unroll
            for (int ct = 0; ct < 3; ++ct) {
                int c = 48 * wc + 16 * ct + l15;
                int sp = (kk2 * 4 + lg) ^ (c & 7);
                short8 bf = *(const short8*)(wb + c * 128 + sp * 16);
                acc[ct] = __builtin_amdgcn_mfma_f32_16x16x32_bf16(a, bf, acc[ct], 0, 0, 0);
            }
        }
        if (ks < 15) {
            uint2 ua; ua.x = packbf(xa.x, xa.y); ua.y = packbf(xa.z, xa.w);
            *(uint2*)&xlds[cur ^ 1][xr * 72 + xcf] = ua;
        }
    }

    #pragma unroll
    for (int ct = 0; ct < 3; ++ct) {
        int col = 48 * wc + 16 * ct + l15;
        if (col < 128) {
            unsigned short* dst = (col < 64) ? qb : kb;
            int n = col & 63;
            #pragma unroll
            for (int r = 0; r < 4; ++r) {
                int t = tb + 16 * wr + lg * 4 + r;
                dst[((long)b * T_ + t) * H_ + n] = f2bf(acc[ct][r]);
            }
        }
    }
    float* vbuf = (float*)&wlds[0][0];             // [32][68] fp32 = 8704B
    #pragma unroll
    for (int ct = 0; ct < 3; ++ct) {
        int col = 48 * wc + 16 * ct + l15;
        if (col >= 128) {
            int h = col - 128;
            #pragma unroll
            for (int r = 0; r < 4; ++r)
                vbuf[(16 * wr + lg * 4 + r) * 68 + h] = acc[ct][r];
        }
    }
    __syncthreads();
    {
        int h = tid >> 3, tc = (tid & 7) * 4;
        uint2 o;
        o.x = packbf(vbuf[(tc + 0) * 68 + h], vbuf[(tc + 1) * 68 + h]);
        o.y = packbf(vbuf[(tc + 2) * 68 + h], vbuf[(tc + 3) * 68 + h]);
        *(uint2*)&vt[((long)b * H_ + h) * T_ + tb + tc] = o;
    }
}

// ---------------- kernel 2a: column partial sums of exp(score) ----------------------
// v5 = v4 + prefetch DISTANCE 2 (3 LDS buffers, rolling vmcnt(4)): tile i's loads
// issued two steps (~1600cy) before use -> L2 latency fully covered.
__global__ __launch_bounds__(256) void col_partial(const unsigned short* __restrict__ qb,
                                                   const unsigned short* __restrict__ kb,
                                                   float* __restrict__ colD) {
    __shared__ unsigned short qlds[3][64 * 64];    // 3 x 8KB
    int tid = threadIdx.x, lane = tid & 63, w = tid >> 6;
    int l15 = lane & 15, lg = lane >> 4;
    int bid = blockIdx.x;
    int p = bid & 3, j = (bid >> 2) & 31, b = bid >> 7;
    int sb = 64 * j + 16 * w;                      // wave's column base

    const unsigned short* kp = kb + ((long)b * T_ + sb + l15) * H_;
    short8 bk0 = *(const short8*)(kp + lg * 8);
    short8 bk1 = *(const short8*)(kp + 32 + lg * 8);

    int l8 = lane >> 3, s8 = lane & 7;
    int swz8 = (s8 ^ l8) * 8;
    const unsigned short* qg = qb + ((long)b * T_ + w * 16 + l8) * H_ + swz8;

    float d = 0.f;
    int first = 64 * j + 64 * p;
    int m = (first < T_) ? ((T_ - first + 255) >> 8) : 0;

    if (m > 0) {
        unsigned short* qd = &qlds[0][w * 16 * 64];
        glds16(qg + (long)first * H_, qd);
        glds16(qg + (long)first * H_ + 8 * H_, qd + 8 * 64);
    }
    if (m > 1) {
        long t1 = first + 256;
        unsigned short* qd = &qlds[1][w * 16 * 64];
        glds16(qg + t1 * H_, qd);
        glds16(qg + t1 * H_ + 8 * H_, qd + 8 * 64);
    }

    for (int i = 0; i < m; ++i) {
        __builtin_amdgcn_s_barrier();              // b1: compute(i-1) done -> buf (i+2)%3 free
        __builtin_amdgcn_sched_barrier(0);
        if (i + 2 < m) {
            long tn = first + 256 * (i + 2);
            unsigned short* qd = &qlds[(i + 2) % 3][w * 16 * 64];
            glds16(qg + tn * H_, qd);
            glds16(qg + tn * H_ + 8 * H_, qd + 8 * 64);
            asm volatile("s_waitcnt vmcnt(4)" ::: "memory");   // tiles i+1,i+2 in flight
        } else if (i + 1 < m) {
            asm volatile("s_waitcnt vmcnt(2)" ::: "memory");   // tile i+1 in flight
        } else {
            asm volatile("s_waitcnt vmcnt(0)" ::: "memory");
        }
        __builtin_amdgcn_sched_barrier(0);
        __builtin_amdgcn_s_barrier();              // b2: buf i%3 ready
        __builtin_amdgcn_sched_barrier(0);

        int t_base = first + 256 * i;
        const unsigned short* qt = &qlds[i % 3][0];
        bool diag = (t_base == 64 * j);            // only p==0, i==0
        #pragma unroll
        for (int st = 0; st < 4; ++st) {
            if (diag && st < w) continue;          // fully-masked subtile
            int trow = 16 * st + l15;
            short8 a0 = *(const short8*)&qt[trow * 64 + ((0 + lg) ^ (trow & 7)) * 8];
            short8 a1 = *(const short8*)&qt[trow * 64 + ((4 + lg) ^ (trow & 7)) * 8];
            f32x4 acc = (f32x4){0.f, 0.f, 0.f, 0.f};
            acc = __builtin_amdgcn_mfma_f32_16x16x32_bf16(a0, bk0, acc, 0, 0, 0);
            acc = __builtin_amdgcn_mfma_f32_16x16x32_bf16(a1, bk1, acc, 0, 0, 0);
            if (diag && st == w) {                 // partial diagonal tile
                #pragma unroll
                for (int r = 0; r < 4; ++r) {
                    float e = __expf(acc[r] * SCALE);
                    if ((16 * st + lg * 4 + r) < (16 * w + l15)) e = 0.f;   // t < s
                    d += e;
                }
            } else {
                #pragma unroll
                for (int r = 0; r < 4; ++r)
                    d += __expf(acc[r] * SCALE);
            }
        }
    }
    d += __shfl_xor(d, 16, 64);
    d += __shfl_xor(d, 32, 64);
    if (lane < 16)
        colD[(long)p * (B_ * T_) + (long)b * T_ + sb + lane] = d;
}

// ---------------- kernel 2b: finalize colR = 1/sum(colD) + zero d_out ---------------
__global__ __launch_bounds__(256) void finalize(const float* __restrict__ colD,
                                                float* __restrict__ colR,
                                                float* __restrict__ out) {
    int tid = threadIdx.x;
    long bid = blockIdx.x;
    uint4 z = (uint4){0u, 0u, 0u, 0u};
    *(uint4*)(out + (bid * 256 + tid) * 4) = z;    // 1024 blocks x 4KB = 4MB
    if (bid < 64) {
        int i = (int)bid * 256 + tid;              // 16384 columns
        float s = colD[i] + colD[B_ * T_ + i] + colD[2 * B_ * T_ + i] + colD[3 * B_ * T_ + i];
        colR[i] = 1.0f / s;
    }
}

// ---------------- kernel 3: out[t,h] = sum_{s<=t} exp(score)*R[s] * v[s,h] ----------
// v4 = R17 2-way + prefetch DISTANCE 2 (3 KV buffers, rolling vmcnt(8)).
// LDS 54.3KB -> 2 blocks/CU; latency hidden by depth instead of block TLP.
__global__ __launch_bounds__(256, 2) void attn_out(const unsigned short* __restrict__ qb,
                                                   const unsigned short* __restrict__ kb,
                                                   const unsigned short* __restrict__ vt,
                                                   const float* __restrict__ colR,
                                                   float* __restrict__ out) {
    __shared__ unsigned short kv[3][8192];        // [buf][ K 64x64 | V 64x64 ]  48 KB
    __shared__ unsigned short pbuf[4][16 * 40];   // per-wave P [16 q][32 s]      5 KB

    int tid = threadIdx.x, lane = tid & 63, w = tid >> 6;
    int qw = w & 1, sw = w >> 1;
    int l15 = lane & 15, lg = lane >> 4;
    int idx = blockIdx.x;
    int p = idx & 1;
    int b = (idx >> 1) & 7;
    int j = 63 - (idx >> 4);
    int t0 = j * 32;

    const unsigned short* kbase = kb + (long)b * T_ * H_;
    const unsigned short* vbase = vt + (long)b * H_ * T_;
    const float* cR = colR + b * T_;

    const unsigned short* qp = qb + ((long)b * T_ + t0 + qw * 16 + l15) * H_ + lg * 8;
    short8 qa0 = *(const short8*)qp;
    short8 qa1 = *(const short8*)(qp + 32);

    int l8 = lane >> 3, s8 = lane & 7;
    int swz8 = (s8 ^ l8) * 8;
    const unsigned short* kg = kbase + (long)(w * 16 + l8) * H_ + swz8;
    const unsigned short* vg = vbase + (long)(w * 16 + l8) * T_ + swz8;

    f32x4 o[4];
    #pragma unroll
    for (int i = 0; i < 4; ++i) o[i] = (f32x4){0.f, 0.f, 0.f, 0.f};
    unsigned short* myp = pbuf[w];

    int nstt = j / 2 + 1;
    int m = (nstt - p + 1) >> 1;                  // # of s-tiles for this block
    int off = (m > 0) ? (j % m) : 0;              // per-block rotation

    if (m > 0) {                                   // prologue: stage rot(0) -> buf0
        int r0i = off;                             // (0+off)%m
        int s0 = (p + 2 * r0i) * 64;
        unsigned short* kd = &kv[0][w * 16 * 64];
        unsigned short* vd = &kv[0][4096 + w * 16 * 64];
        glds16(kg + (long)s0 * H_, kd);  glds16(kg + (long)s0 * H_ + 8 * H_, kd + 8 * 64);
        glds16(vg + s0, vd);             glds16(vg + s0 + 8 * T_, vd + 8 * 64);
    }
    if (m > 1) {                                   // prologue: stage rot(1) -> buf1
        int r1i = 1 + off; if (r1i >= m) r1i -= m;
        int s1 = (p + 2 * r1i) * 64;
        unsigned short* kd = &kv[1][w * 16 * 64];
        unsigned short* vd = &kv[1][4096 + w * 16 * 64];
        glds16(kg + (long)s1 * H_, kd);  glds16(kg + (long)s1 * H_ + 8 * H_, kd + 8 * 64);
        glds16(vg + s1, vd);             glds16(vg + s1 + 8 * T_, vd + 8 * 64);
    }

    for (int i = 0; i < m; ++i) {
        __builtin_amdgcn_s_barrier();              // b1: compute(i-1) done -> buf (i+2)%3 free
        __builtin_amdgcn_sched_barrier(0);
        if (i + 2 < m) {
            int rot = i + 2 + off; while (rot >= m) rot -= m;
            int sn = (p + 2 * rot) * 64;
            unsigned short* kd = &kv[(i + 2) % 3][w * 16 * 64];
            unsigned short* vd = &kv[(i + 2) % 3][4096 + w * 16 * 64];
            glds16(kg + (long)sn * H_, kd);
            glds16(kg + (long)sn * H_ + 8 * H_, kd + 8 * 64);
            glds16(vg + sn, vd);
            glds16(vg + sn + 8 * T_, vd + 8 * 64);
            asm volatile("s_waitcnt vmcnt(8)" ::: "memory");   // tiles i+1,i+2 in flight
        } else if (i + 1 < m) {
            asm volatile("s_waitcnt vmcnt(4)" ::: "memory");   // tile i+1 in flight
        } else {
            asm volatile("s_waitcnt vmcnt(0)" ::: "memory");
        }
        __builtin_amdgcn_sched_barrier(0);
        __builtin_amdgcn_s_barrier();              // b2: buf i%3 ready
        __builtin_amdgcn_sched_barrier(0);

        int rotc = i + off; while (rotc >= m) rotc -= m;
        int s0 = (p + 2 * rotc) * 64;
        const unsigned short* kt = &kv[i % 3][0];
        const unsigned short* vtl = &kv[i % 3][4096];

        #pragma unroll
        for (int ct = 0; ct < 2; ++ct) {
            int row = sw * 32 + ct * 16 + l15;
            short8 k0 = *(const short8*)&kt[row * 64 + ((0 + lg) ^ (row & 7)) * 8];
            short8 k1 = *(const short8*)&kt[row * 64 + ((4 + lg) ^ (row & 7)) * 8];
            f32x4 acc = (f32x4){0.f, 0.f, 0.f, 0.f};
            acc = __builtin_amdgcn_mfma_f32_16x16x32_bf16(qa0, k0, acc, 0, 0, 0);
            acc = __builtin_amdgcn_mfma_f32_16x16x32_bf16(qa1, k1, acc, 0, 0, 0);
            int s = s0 + row;
            float rr = cR[s];
            #pragma unroll
            for (int r = 0; r < 4; ++r) {
                int t = t0 + qw * 16 + lg * 4 + r;
                float pv = __expf(acc[r] * SCALE) * rr;
                if (s > t) pv = 0.f;
                myp[(lg * 4 + r) * 40 + ct * 16 + l15] = f2bf(pv);
            }
        }
        short8 pa = *(const short8*)&myp[l15 * 40 + lg * 8];
        #pragma unroll
        for (int ht = 0; ht < 4; ++ht) {
            int vrow = ht * 16 + l15;
            short8 vf = *(const short8*)&vtl[vrow * 64 + ((sw * 4 + lg) ^ (vrow & 7)) * 8];
            o[ht] = __builtin_amdgcn_mfma_f32_16x16x32_bf16(pa, vf, o[ht], 0, 0, 0);
        }
    }

    __syncthreads();
    float* rbuf = (float*)&kv[0][0];               // [32 q][68] f32
    if (sw == 1) {
        #pragma unroll
        for (int ht = 0; ht < 4; ++ht)
            #pragma unroll
            for (int r = 0; r < 4; ++r)
                rbuf[(qw * 16 + lg * 4 + r) * 68 + ht * 16 + l15] = o[ht][r];
    }
    __syncthreads();
    if (sw == 0) {
        float* ob = out + ((long)b * T_ + t0 + qw * 16) * H_;
        #pragma unroll
        for (int ht = 0; ht < 4; ++ht)
            #pragma unroll
            for (int r = 0; r < 4; ++r) {
                int rr_ = lg * 4 + r, cc = ht * 16 + l15;
                unsafeAtomicAdd(&ob[(long)rr_ * H_ + cc],
                                o[ht][r] + rbuf[(qw * 16 + rr_) * 68 + cc]);
            }
    }
}

extern "C" void kernel_launch(void* const* d_in, const int* in_sizes, int n_in,
                              void* d_out, int out_size, void* d_ws, size_t ws_size,
                              hipStream_t stream) {
    const float* x  = (const float*)d_in[0];
    const float* Wk = (const float*)d_in[1];
    const float* Wq = (const float*)d_in[2];
    const float* Wv = (const float*)d_in[3];
    float* out = (float*)d_out;

    char* ws = (char*)d_ws;
    unsigned short* Wt = (unsigned short*)ws;                                  // 393216 B
    unsigned short* qb = (unsigned short*)(ws + 393216);                       // 2 MB
    unsigned short* kb = (unsigned short*)(ws + 393216 + 2097152);             // 2 MB
    unsigned short* vt = (unsigned short*)(ws + 393216 + 2 * 2097152);         // 2 MB
    float* colR = (float*)(ws + 393216 + 3 * 2097152);                         // 64 KB
    float* colD = colR + B_ * T_;                                              // 256 KB

    prep_w     <<<48,   256, 0, stream>>>(Wq, Wk, Wv, Wt);
    qkv_gemm   <<<512,  512, 0, stream>>>(x, Wt, qb, kb, vt);
    col_partial<<<1024, 256, 0, stream>>>(qb, kb, colD);
    finalize   <<<1024, 256, 0, stream>>>(colD, colR, out);
    attn_out   <<<1024, 256, 0, stream>>>(qb, kb, vt, colR, out);
}

// Round 23
// 57.726 us; speedup vs baseline: 1.0500x; 1.0500x over previous
//
#include <hip/hip_runtime.h>
#include <hip/hip_bf16.h>

typedef __attribute__((ext_vector_type(8))) short short8;   // bf16x8 MFMA frag
typedef __attribute__((ext_vector_type(4))) float f32x4;    // fp32x4 acc

#define B_  8
#define T_  2048
#define E_  1024
#define H_  64
#define SCALE 0.03125f   // 1024^-0.5

__device__ inline unsigned short f2bf(float f) {
    unsigned int u = __builtin_bit_cast(unsigned int, f);
    unsigned int r = (u + 0x7FFFu + ((u >> 16) & 1u)) >> 16;   // RNE
    return (unsigned short)r;
}
__device__ inline unsigned int packbf(float lo, float hi) {
    return (unsigned int)f2bf(lo) | ((unsigned int)f2bf(hi) << 16);
}
__device__ inline void glds16(const void* g, void* l) {
    __builtin_amdgcn_global_load_lds((const __attribute__((address_space(1))) void*)g,
                                     (__attribute__((address_space(3))) void*)l, 16, 0, 0);
}

// ------------- kernel 0: W fp32 [1024][64] -> Wt bf16 [192][1024] (transposed) -------
__global__ __launch_bounds__(256) void prep_w(const float* __restrict__ Wq,
                                              const float* __restrict__ Wk,
                                              const float* __restrict__ Wv,
                                              unsigned short* __restrict__ Wt) {
    __shared__ float ls[64][65];
    int tid = threadIdx.x;
    int wsel = blockIdx.x >> 4, kt = blockIdx.x & 15;
    const float* W = (wsel == 0) ? Wq : (wsel == 1) ? Wk : Wv;
    int kr = tid >> 2, c4 = (tid & 3) * 16;
    const float* src = W + (long)(kt * 64 + kr) * H_ + c4;
    #pragma unroll
    for (int i = 0; i < 4; ++i) {
        float4 v = *(const float4*)(src + 4 * i);
        ls[kr][c4 + 4 * i + 0] = v.x; ls[kr][c4 + 4 * i + 1] = v.y;
        ls[kr][c4 + 4 * i + 2] = v.z; ls[kr][c4 + 4 * i + 3] = v.w;
    }
    __syncthreads();
    int c = tid >> 2, kk = (tid & 3) * 16;
    unsigned short* dst = Wt + (long)(wsel * 64 + c) * E_ + kt * 64 + kk;
    uint4 o1, o2;
    o1.x = packbf(ls[kk + 0][c], ls[kk + 1][c]);  o1.y = packbf(ls[kk + 2][c], ls[kk + 3][c]);
    o1.z = packbf(ls[kk + 4][c], ls[kk + 5][c]);  o1.w = packbf(ls[kk + 6][c], ls[kk + 7][c]);
    o2.x = packbf(ls[kk + 8][c], ls[kk + 9][c]);  o2.y = packbf(ls[kk + 10][c], ls[kk + 11][c]);
    o2.z = packbf(ls[kk + 12][c], ls[kk + 13][c]);o2.w = packbf(ls[kk + 14][c], ls[kk + 15][c]);
    *(uint4*)dst = o1;
    *(uint4*)(dst + 8) = o2;
}

// ---------------- kernel 1: QKV GEMM  [16384,1024] @ [1024,192] --------------------
// R15 version (verified; 16.9us measured via duplicate-launch attribution).
__global__ __launch_bounds__(512, 4) void qkv_gemm(const float* __restrict__ x,
                                                   const unsigned short* __restrict__ Wt,
                                                   unsigned short* __restrict__ qb,
                                                   unsigned short* __restrict__ kb,
                                                   unsigned short* __restrict__ vt) {
    __shared__ unsigned short wlds[2][192 * 64];   // 49152 B, linear (glds dest)
    __shared__ unsigned short xlds[2][32 * 72];    // 9216 B, padded stride 144B

    int tid = threadIdx.x, lane = tid & 63, w = tid >> 6;   // 8 waves
    int l15 = lane & 15, lg = lane >> 4;
    int wr = w & 1, wc = w >> 1;                   // row half / col quarter
    int r0 = blockIdx.x * 32;
    int b = r0 >> 11, tb = r0 & 2047;

    int l8 = lane >> 3, s8 = lane & 7;
    int swz = s8 ^ l8;
    const unsigned short* wg = Wt + (long)(24 * w + l8) * E_ + swz * 8;
    unsigned short* wl0 = &wlds[0][(24 * w) * 64];
    unsigned short* wl1 = &wlds[1][(24 * w) * 64];

    int xr = tid >> 4, xcf = (tid & 15) * 4;
    const float* xg = x + (long)(r0 + xr) * E_ + xcf;

    f32x4 acc[3];
    #pragma unroll
    for (int i = 0; i < 3; ++i) acc[i] = (f32x4){0.f, 0.f, 0.f, 0.f};

    {
        float4 xa = *(const float4*)xg;
        #pragma unroll
        for (int j = 0; j < 3; ++j)
            glds16(wg + (long)(8 * j) * E_, wl0 + (8 * j) * 64);
        uint2 ua; ua.x = packbf(xa.x, xa.y); ua.y = packbf(xa.z, xa.w);
        *(uint2*)&xlds[0][xr * 72 + xcf] = ua;
    }

    for (int ks = 0; ks < 16; ++ks) {
        int cur = ks & 1;
        __builtin_amdgcn_s_barrier();              // b1: all waves done with prev compute
        __builtin_amdgcn_sched_barrier(0);
        float4 xa;
        if (ks < 15) {
            int kp = (ks + 1) * 64;
            xa = *(const float4*)(xg + kp);        // 1 vmem
            unsigned short* wldst = cur ? wl0 : wl1;
            #pragma unroll
            for (int j = 0; j < 3; ++j)            // 3 vmem (glds)
                glds16(wg + (long)(8 * j) * E_ + kp, wldst + (8 * j) * 64);
            asm volatile("s_waitcnt vmcnt(4) lgkmcnt(0)" ::: "memory");
        } else {
            asm volatile("s_waitcnt vmcnt(0) lgkmcnt(0)" ::: "memory");
        }
        __builtin_amdgcn_sched_barrier(0);
        __builtin_amdgcn_s_barrier();              // b2: buf cur ready for everyone
        __builtin_amdgcn_sched_barrier(0);

        const char* wb = (const char*)&wlds[cur][0];
        const char* xsb = (const char*)&xlds[cur][0];
        #pragma unroll
        for (int kk2 = 0; kk2 < 2; ++kk2) {
            short8 a = *(const short8*)(xsb + (16 * wr + l15) * 144 + kk2 * 64 + lg * 16);
            #pragma unroll
            for (int ct = 0; ct < 3; ++ct) {
                int c = 48 * wc + 16 * ct + l15;
                int sp = (kk2 * 4 + lg) ^ (c & 7);
                short8 bf = *(const short8*)(wb + c * 128 + sp * 16);
                acc[ct] = __builtin_amdgcn_mfma_f32_16x16x32_bf16(a, bf, acc[ct], 0, 0, 0);
            }
        }
        if (ks < 15) {
            uint2 ua; ua.x = packbf(xa.x, xa.y); ua.y = packbf(xa.z, xa.w);
            *(uint2*)&xlds[cur ^ 1][xr * 72 + xcf] = ua;
        }
    }

    #pragma unroll
    for (int ct = 0; ct < 3; ++ct) {
        int col = 48 * wc + 16 * ct + l15;
        if (col < 128) {
            unsigned short* dst = (col < 64) ? qb : kb;
            int n = col & 63;
            #pragma unroll
            for (int r = 0; r < 4; ++r) {
                int t = tb + 16 * wr + lg * 4 + r;
                dst[((long)b * T_ + t) * H_ + n] = f2bf(acc[ct][r]);
            }
        }
    }
    float* vbuf = (float*)&wlds[0][0];             // [32][68] fp32 = 8704B
    #pragma unroll
    for (int ct = 0; ct < 3; ++ct) {
        int col = 48 * wc + 16 * ct + l15;
        if (col >= 128) {
            int h = col - 128;
            #pragma unroll
            for (int r = 0; r < 4; ++r)
                vbuf[(16 * wr + lg * 4 + r) * 68 + h] = acc[ct][r];
        }
    }
    __syncthreads();
    {
        int h = tid >> 3, tc = (tid & 7) * 4;
        uint2 o;
        o.x = packbf(vbuf[(tc + 0) * 68 + h], vbuf[(tc + 1) * 68 + h]);
        o.y = packbf(vbuf[(tc + 2) * 68 + h], vbuf[(tc + 3) * 68 + h]);
        *(uint2*)&vt[((long)b * H_ + h) * T_ + tb + tc] = o;
    }
}

// ---------------- kernel 2: column partial sums of exp(score) + zero d_out ----------
// R21 version (verified, 2-buffer dist-1) + d_out zeroing folded in (grid is exactly
// 1024x256: 16B/thread = 4MB; stream order precedes attn_out's atomics).
__global__ __launch_bounds__(256) void col_partial(const unsigned short* __restrict__ qb,
                                                   const unsigned short* __restrict__ kb,
                                                   float* __restrict__ colD,
                                                   float* __restrict__ outz) {
    __shared__ unsigned short qlds[2][64 * 64];    // 2 x 8KB
    int tid = threadIdx.x, lane = tid & 63, w = tid >> 6;
    int l15 = lane & 15, lg = lane >> 4;
    int bid = blockIdx.x;
    {
        uint4 z = (uint4){0u, 0u, 0u, 0u};
        *(uint4*)(outz + ((long)bid * 256 + tid) * 4) = z;
    }
    int p = bid & 3, j = (bid >> 2) & 31, b = bid >> 7;
    int sb = 64 * j + 16 * w;                      // wave's column base

    const unsigned short* kp = kb + ((long)b * T_ + sb + l15) * H_;
    short8 bk0 = *(const short8*)(kp + lg * 8);
    short8 bk1 = *(const short8*)(kp + 32 + lg * 8);

    int l8 = lane >> 3, s8 = lane & 7;
    int swz8 = (s8 ^ l8) * 8;
    const unsigned short* qg = qb + ((long)b * T_ + w * 16 + l8) * H_ + swz8;
    unsigned short* qd0 = &qlds[0][w * 16 * 64];
    unsigned short* qd1 = &qlds[1][w * 16 * 64];

    float d = 0.f;
    int first = 64 * j + 64 * p;
    int m = (first < T_) ? ((T_ - first + 255) >> 8) : 0;

    if (m > 0) {
        glds16(qg + (long)first * H_, qd0);
        glds16(qg + (long)first * H_ + 8 * H_, qd0 + 8 * 64);
    }

    for (int i = 0; i < m; ++i) {
        int cur = i & 1;
        __builtin_amdgcn_s_barrier();
        __builtin_amdgcn_sched_barrier(0);
        if (i + 1 < m) {
            long tn = first + 256 * (i + 1);
            unsigned short* qd = cur ? qd0 : qd1;
            glds16(qg + tn * H_, qd);
            glds16(qg + tn * H_ + 8 * H_, qd + 8 * 64);
            asm volatile("s_waitcnt vmcnt(2)" ::: "memory");
        } else {
            asm volatile("s_waitcnt vmcnt(0)" ::: "memory");
        }
        __builtin_amdgcn_sched_barrier(0);
        __builtin_amdgcn_s_barrier();
        __builtin_amdgcn_sched_barrier(0);

        int t_base = first + 256 * i;
        const unsigned short* qt = &qlds[cur][0];
        bool diag = (t_base == 64 * j);            // only p==0, i==0
        #pragma unroll
        for (int st = 0; st < 4; ++st) {
            if (diag && st < w) continue;          // fully-masked subtile
            int trow = 16 * st + l15;
            short8 a0 = *(const short8*)&qt[trow * 64 + ((0 + lg) ^ (trow & 7)) * 8];
            short8 a1 = *(const short8*)&qt[trow * 64 + ((4 + lg) ^ (trow & 7)) * 8];
            f32x4 acc = (f32x4){0.f, 0.f, 0.f, 0.f};
            acc = __builtin_amdgcn_mfma_f32_16x16x32_bf16(a0, bk0, acc, 0, 0, 0);
            acc = __builtin_amdgcn_mfma_f32_16x16x32_bf16(a1, bk1, acc, 0, 0, 0);
            if (diag && st == w) {                 // partial diagonal tile
                #pragma unroll
                for (int r = 0; r < 4; ++r) {
                    float e = __expf(acc[r] * SCALE);
                    if ((16 * st + lg * 4 + r) < (16 * w + l15)) e = 0.f;   // t < s
                    d += e;
                }
            } else {
                #pragma unroll
                for (int r = 0; r < 4; ++r)
                    d += __expf(acc[r] * SCALE);
            }
        }
    }
    d += __shfl_xor(d, 16, 64);
    d += __shfl_xor(d, 32, 64);
    if (lane < 16)
        colD[(long)p * (B_ * T_) + (long)b * T_ + sb + lane] = d;
}

// ---------------- kernel 3: out[t,h] = sum_{s<=t} exp(score)/D[s] * v[s,h] ----------
// R21 2-buffer version; colR inlined: rr = 1/(colD0+..+colD3) (fixed order, det.).
__global__ __launch_bounds__(256, 4) void attn_out(const unsigned short* __restrict__ qb,
                                                   const unsigned short* __restrict__ kb,
                                                   const unsigned short* __restrict__ vt,
                                                   const float* __restrict__ colD,
                                                   float* __restrict__ out) {
    __shared__ unsigned short kv[2][8192];        // [buf][ K 64x64 | V 64x64 ]  32 KB
    __shared__ unsigned short pbuf[4][16 * 40];   // per-wave P [16 q][32 s]      5 KB

    int tid = threadIdx.x, lane = tid & 63, w = tid >> 6;
    int qw = w & 1, sw = w >> 1;
    int l15 = lane & 15, lg = lane >> 4;
    int idx = blockIdx.x;
    int p = idx & 1;
    int b = (idx >> 1) & 7;
    int j = 63 - (idx >> 4);
    int t0 = j * 32;

    const unsigned short* kbase = kb + (long)b * T_ * H_;
    const unsigned short* vbase = vt + (long)b * H_ * T_;
    const float* cD = colD + (long)b * T_;

    const unsigned short* qp = qb + ((long)b * T_ + t0 + qw * 16 + l15) * H_ + lg * 8;
    short8 qa0 = *(const short8*)qp;
    short8 qa1 = *(const short8*)(qp + 32);

    int l8 = lane >> 3, s8 = lane & 7;
    int swz8 = (s8 ^ l8) * 8;
    const unsigned short* kg = kbase + (long)(w * 16 + l8) * H_ + swz8;
    const unsigned short* vg = vbase + (long)(w * 16 + l8) * T_ + swz8;
    unsigned short* kd0 = &kv[0][w * 16 * 64];
    unsigned short* vd0 = &kv[0][4096 + w * 16 * 64];
    unsigned short* kd1 = &kv[1][w * 16 * 64];
    unsigned short* vd1 = &kv[1][4096 + w * 16 * 64];

    f32x4 o[4];
    #pragma unroll
    for (int i = 0; i < 4; ++i) o[i] = (f32x4){0.f, 0.f, 0.f, 0.f};
    unsigned short* myp = pbuf[w];

    int nstt = j / 2 + 1;
    int m = (nstt - p + 1) >> 1;                  // # of s-tiles for this block
    int off = (m > 0) ? (j % m) : 0;              // per-block rotation

    if (m > 0) {
        int s0 = (p + 2 * off) * 64;
        glds16(kg + (long)s0 * H_, kd0);  glds16(kg + (long)s0 * H_ + 8 * H_, kd0 + 8 * 64);
        glds16(vg + s0, vd0);             glds16(vg + s0 + 8 * T_, vd0 + 8 * 64);
    }

    for (int i = 0; i < m; ++i) {
        int cur = i & 1;
        __builtin_amdgcn_s_barrier();
        __builtin_amdgcn_sched_barrier(0);
        if (i + 1 < m) {
            int rot = i + 1 + off; if (rot >= m) rot -= m;
            int sn = (p + 2 * rot) * 64;
            unsigned short* kd = cur ? kd0 : kd1;
            unsigned short* vd = cur ? vd0 : vd1;
            glds16(kg + (long)sn * H_, kd);
            glds16(kg + (long)sn * H_ + 8 * H_, kd + 8 * 64);
            glds16(vg + sn, vd);
            glds16(vg + sn + 8 * T_, vd + 8 * 64);
            asm volatile("s_waitcnt vmcnt(4)" ::: "memory");
        } else {
            asm volatile("s_waitcnt vmcnt(0)" ::: "memory");
        }
        __builtin_amdgcn_sched_barrier(0);
        __builtin_amdgcn_s_barrier();
        __builtin_amdgcn_sched_barrier(0);

        int rotc = i + off; if (rotc >= m) rotc -= m;
        int s0 = (p + 2 * rotc) * 64;
        const unsigned short* kt = &kv[cur][0];
        const unsigned short* vtl = &kv[cur][4096];

        #pragma unroll
        for (int ct = 0; ct < 2; ++ct) {
            int row = sw * 32 + ct * 16 + l15;
            short8 k0 = *(const short8*)&kt[row * 64 + ((0 + lg) ^ (row & 7)) * 8];
            short8 k1 = *(const short8*)&kt[row * 64 + ((4 + lg) ^ (row & 7)) * 8];
            f32x4 acc = (f32x4){0.f, 0.f, 0.f, 0.f};
            acc = __builtin_amdgcn_mfma_f32_16x16x32_bf16(qa0, k0, acc, 0, 0, 0);
            acc = __builtin_amdgcn_mfma_f32_16x16x32_bf16(qa1, k1, acc, 0, 0, 0);
            int s = s0 + row;
            float rr = 1.0f / (cD[s] + cD[B_ * T_ + s] + cD[2 * B_ * T_ + s] + cD[3 * B_ * T_ + s]);
            #pragma unroll
            for (int r = 0; r < 4; ++r) {
                int t = t0 + qw * 16 + lg * 4 + r;
                float pv = __expf(acc[r] * SCALE) * rr;
                if (s > t) pv = 0.f;
                myp[(lg * 4 + r) * 40 + ct * 16 + l15] = f2bf(pv);
            }
        }
        short8 pa = *(const short8*)&myp[l15 * 40 + lg * 8];
        #pragma unroll
        for (int ht = 0; ht < 4; ++ht) {
            int vrow = ht * 16 + l15;
            short8 vf = *(const short8*)&vtl[vrow * 64 + ((sw * 4 + lg) ^ (vrow & 7)) * 8];
            o[ht] = __builtin_amdgcn_mfma_f32_16x16x32_bf16(pa, vf, o[ht], 0, 0, 0);
        }
    }

    __syncthreads();
    float* rbuf = (float*)&kv[0][0];               // [32 q][68] f32
    if (sw == 1) {
        #pragma unroll
        for (int ht = 0; ht < 4; ++ht)
            #pragma unroll
            for (int r = 0; r < 4; ++r)
                rbuf[(qw * 16 + lg * 4 + r) * 68 + ht * 16 + l15] = o[ht][r];
    }
    __syncthreads();
    if (sw == 0) {
        float* ob = out + ((long)b * T_ + t0 + qw * 16) * H_;
        #pragma unroll
        for (int ht = 0; ht < 4; ++ht)
            #pragma unroll
            for (int r = 0; r < 4; ++r) {
                int rr_ = lg * 4 + r, cc = ht * 16 + l15;
                unsafeAtomicAdd(&ob[(long)rr_ * H_ + cc],
                                o[ht][r] + rbuf[(qw * 16 + rr_) * 68 + cc]);
            }
    }
}

extern "C" void kernel_launch(void* const* d_in, const int* in_sizes, int n_in,
                              void* d_out, int out_size, void* d_ws, size_t ws_size,
                              hipStream_t stream) {
    const float* x  = (const float*)d_in[0];
    const float* Wk = (const float*)d_in[1];
    const float* Wq = (const float*)d_in[2];
    const float* Wv = (const float*)d_in[3];
    float* out = (float*)d_out;

    char* ws = (char*)d_ws;
    unsigned short* Wt = (unsigned short*)ws;                                  // 393216 B
    unsigned short* qb = (unsigned short*)(ws + 393216);                       // 2 MB
    unsigned short* kb = (unsigned short*)(ws + 393216 + 2097152);             // 2 MB
    unsigned short* vt = (unsigned short*)(ws + 393216 + 2 * 2097152);         // 2 MB
    float* colD = (float*)(ws + 393216 + 3 * 2097152);                         // 256 KB

    prep_w     <<<48,   256, 0, stream>>>(Wq, Wk, Wv, Wt);
    qkv_gemm   <<<512,  512, 0, stream>>>(x, Wt, qb, kb, vt);
    col_partial<<<1024, 256, 0, stream>>>(qb, kb, colD, out);
    attn_out   <<<1024, 256, 0, stream>>>(qb, kb, vt, colD, out);
}